// Round 2
// 686.790 us; speedup vs baseline: 1.0342x; 1.0342x over previous
//
#include <hip/hip_runtime.h>
#include <stdint.h>

// HashGrid forward, R4b (R4 + compile fix: NT builtins need builtin vector
// types, not HIP_vector_type structs -> ext_vector_type wrappers).
// R3 counters: merge = 201 us (1.74 TB/s, VALUBusy 7.8%, Occ 39%) -> latency-
// bound at the 50% occupancy cap from its 36 KB LDS buffer. The 8 level
// kernels = ~509 us total (~64 us each) vs a ~20 us/kernel L2-BW bound ->
// their 4 MB tables are NOT staying L2-resident: the x-read and ws-write
// streams share the same per-XCD L2 and thrash the table, and 1 pt/thread
// gives only 4 gathers in flight.
// R4 changes:
//  (a) hash8_kernel: ONE launch for levels 8..15, level = 8 + blockIdx%8.
//      Round-robin block->XCD dispatch pins each level's table to one XCD's
//      private 4 MB L2 (levels 8..15 are each <= 4 MB). x loads and ws stores
//      are nontemporal so the streams can't evict the table. 4 points/thread
//      -> 16 independent gathers in flight.
//  (b) merge8_kernel: two-phase LDS transpose with a 128-row buffer
//      (18.4 KB -> 8 blocks/CU, occupancy cap 100% instead of 50%); level
//      results staged in 32 VGPRs; NT loads for ws/x (read-once streams),
//      NT stores for out (keeps dense tables 0-7, 1.1 MB, hot in L2).
//
// Correctness-critical (unchanged from R3, passed at 4.8e-7): pos = x*scale
// + 0.5 as separate __fmul_rn/__fadd_rn (no FMA contraction -> floor() cell
// matches numpy); fmaf accumulation order (0,0),(0,1),(1,0),(1,1); ws
// round-trips float2 bits exactly (u64 NT store/load).

constexpr int      kNPoints = 2097152;
constexpr uint32_t kT       = 524288u;      // 2^19
constexpr uint32_t kTMask   = kT - 1u;
constexpr uint32_t kPrimeY  = 2654435761u;  // tcnn 2D spatial-hash prime

typedef float vf4 __attribute__((ext_vector_type(4)));

__device__ __forceinline__ float2 nt_load_f2(const float2* p) {
    // float2 is an 8-byte aligned struct; load its bits as u64 (NT-legal type).
    union { unsigned long long u; float2 f2; } u;
    u.u = __builtin_nontemporal_load(reinterpret_cast<const unsigned long long*>(p));
    return u.f2;
}

__device__ __forceinline__ void nt_store_f2(float2* p, float2 v) {
    union { unsigned long long u; float2 f2; } u; u.f2 = v;
    __builtin_nontemporal_store(u.u, reinterpret_cast<unsigned long long*>(p));
}

__device__ __forceinline__ void nt_store_f4(float* p, float a, float b, float c, float d) {
    vf4 v; v.x = a; v.y = b; v.z = c; v.w = d;
    __builtin_nontemporal_store(v, reinterpret_cast<vf4*>(p));
}

// scale = 16*1.5^l - 1, exactly fp32-representable for all 16 levels.
__device__ __host__ inline void level_consts(int l, float& sc, uint32_t& re, int& dense) {
    const float ksc[16] = {
        15.0f, 23.0f, 35.0f, 53.0f, 80.0f, 120.5f, 181.25f, 272.375f,
        409.0625f, 614.09375f, 921.640625f, 1382.9609375f,
        2074.94140625f, 3112.912109375f, 4669.8681640625f, 7005.30224609375f};
    const uint32_t kre[16] = {16u, 24u, 36u, 54u, 81u, 122u, 183u, 274u,
                              411u, 616u, 923u, 1384u, 2076u, 3114u, 4671u, 7007u};
    sc = ksc[l]; re = kre[l]; dense = (l < 10) ? 1 : 0;
}

__device__ __forceinline__ float2 encode_one(float2 xy, float scale, uint32_t res,
                                             int dense, const float2* __restrict__ tab) {
    const float px  = __fadd_rn(__fmul_rn(xy.x, scale), 0.5f);
    const float py  = __fadd_rn(__fmul_rn(xy.y, scale), 0.5f);
    const float fpx = floorf(px);
    const float fpy = floorf(py);
    const float fx  = px - fpx;
    const float fy  = py - fpy;
    const uint32_t gx = (uint32_t)fpx;
    const uint32_t gy = (uint32_t)fpy;

    float ax = 0.0f, ay = 0.0f;
#pragma unroll
    for (int dx = 0; dx < 2; ++dx) {
        const uint32_t cx = gx + (uint32_t)dx;
        const float    wx = dx ? fx : (1.0f - fx);
#pragma unroll
        for (int dy = 0; dy < 2; ++dy) {
            const uint32_t cy = gy + (uint32_t)dy;
            const float    wy = dy ? fy : (1.0f - fy);
            const uint32_t idx_d = (cx + cy * res) & kTMask;
            const uint32_t idx_h = (cx ^ (cy * kPrimeY)) & kTMask;
            const uint32_t idx   = dense ? idx_d : idx_h;
            const float2   v     = tab[idx];
            const float    w     = wx * wy;
            ax = fmaf(v.x, w, ax);
            ay = fmaf(v.y, w, ay);
        }
    }
    return make_float2(ax, ay);
}

// ---- hash8: levels 8..15, one level per XCD (blockIdx%8), 4 pts/thread. ----
// Grid: 8 levels * 2048 chunks = 16384 blocks; chunk = 1024 consecutive
// points; thread t handles points base+t+{0,256,512,768} so every vmem
// instruction is a perfectly-coalesced contiguous wave access.
__global__ __launch_bounds__(256) void hash8_kernel(
    const float* __restrict__ x,
    const float* __restrict__ table,
    float2* __restrict__ ws)
{
    const uint32_t slot  = blockIdx.x & 7u;   // -> XCD slot (round-robin dispatch)
    const uint32_t chunk = blockIdx.x >> 3;   // 0..2047
    const int      l     = 8 + (int)slot;
    float sc; uint32_t re; int de;
    level_consts(l, sc, re, de);
    const float2* __restrict__ tab =
        reinterpret_cast<const float2*>(table) + ((size_t)l << 19);
    float2* __restrict__ wsl = ws + (size_t)slot * kNPoints;

    const uint32_t base = chunk * 1024u + threadIdx.x;
    const float2* __restrict__ xv = reinterpret_cast<const float2*>(x);

    float2 xy[4];
#pragma unroll
    for (int k = 0; k < 4; ++k)   // NT: don't let the x stream evict the table
        xy[k] = nt_load_f2(xv + base + (uint32_t)k * 256u);

    float2 r[4];
#pragma unroll
    for (int k = 0; k < 4; ++k)   // 16 independent gathers in flight
        r[k] = encode_one(xy[k], sc, re, de, tab);

#pragma unroll
    for (int k = 0; k < 4; ++k)   // NT: ws write stream bypasses the table's L2
        nt_store_f2(wsl + base + (uint32_t)k * 256u, r[k]);
}

// ---- merge: dense levels 0..7 inline + 8 ws slabs, two-phase LDS transpose. --
__global__ __launch_bounds__(256) void merge8_kernel(
    const float* __restrict__ x,
    const float* __restrict__ table,
    const float2* __restrict__ ws,    // [8][N]
    float* __restrict__ out)
{
    __shared__ float s[128 * 36];     // 18.4 KB: 8 blocks/CU -> occupancy cap 100%
    const uint32_t tid = threadIdx.x;
    const uint32_t n   = blockIdx.x * 256u + tid;
    const float2   xy  = nt_load_f2(reinterpret_cast<const float2*>(x) + n);

    float2 r[16];                     // 32 VGPRs of staged results
#pragma unroll
    for (int l = 0; l < 8; ++l) {
        float sc; uint32_t re; int de;
        level_consts(l, sc, re, de);
        const float2* tab = reinterpret_cast<const float2*>(table) + ((size_t)l << 19);
        r[l] = encode_one(xy, sc, re, de, tab);
    }
#pragma unroll
    for (int j = 0; j < 8; ++j)       // read-once stream: NT keeps L2 for tables
        r[8 + j] = nt_load_f2(ws + (size_t)j * kNPoints + n);

#pragma unroll
    for (int h = 0; h < 2; ++h) {
        if ((tid >> 7) == (uint32_t)h) {          // wave-uniform branch
            const uint32_t p = tid & 127u;
#pragma unroll
            for (int l = 0; l < 16; ++l) {
                s[p * 36 + 2 * l]     = r[l].x;
                s[p * 36 + 2 * l + 1] = r[l].y;
            }
        }
        __syncthreads();
        // 128 rows * 32 floats = 1024 float4 stores, 4 per thread, coalesced.
        float* ob = out + (size_t)blockIdx.x * 8192 + (uint32_t)h * 4096u;
#pragma unroll
        for (int k = 0; k < 4; ++k) {
            const uint32_t q   = tid + (uint32_t)k * 256u;
            const uint32_t row = q >> 3;          // point within half-tile
            const uint32_t c   = (q & 7u) * 4u;   // column (floats)
            const float* sp = &s[row * 36 + c];   // 16B-aligned, conflict-clean b128
            nt_store_f4(ob + q * 4u, sp[0], sp[1], sp[2], sp[3]);
        }
        if (h == 0) __syncthreads();              // before phase-2 overwrites s
    }
}

// ---- Fallback: R1 single kernel (passed at 688 us) if ws is too small. ----
__global__ __launch_bounds__(256) void hashgrid_fwd_fallback(
    const float* __restrict__ x,
    const float* __restrict__ table,
    float* __restrict__ out)
{
    const uint32_t tid = blockIdx.x * blockDim.x + threadIdx.x;
    const uint32_t l   = tid & 15u;
    const uint32_t n   = tid >> 4;
    float sc; uint32_t re; int de;
    level_consts((int)l, sc, re, de);
    const float2 xy = reinterpret_cast<const float2*>(x)[n];
    const float2* tab = reinterpret_cast<const float2*>(table) + ((size_t)l << 19);
    const float2 r = encode_one(xy, sc, re, de, tab);
    reinterpret_cast<float2*>(out)[tid] = r;
}

extern "C" void kernel_launch(void* const* d_in, const int* in_sizes, int n_in,
                              void* d_out, int out_size, void* d_ws, size_t ws_size,
                              hipStream_t stream) {
    const float* x     = (const float*)d_in[0];
    const float* table = (const float*)d_in[1];
    float*       out   = (float*)d_out;

    const size_t need8 = (size_t)8 * kNPoints * sizeof(float2);  // 128 MB

    if (ws_size >= need8) {
        float2* ws = (float2*)d_ws;
        hash8_kernel<<<16384, 256, 0, stream>>>(x, table, ws);
        merge8_kernel<<<kNPoints / 256, 256, 0, stream>>>(x, table, ws, out);
    } else {
        hashgrid_fwd_fallback<<<(kNPoints * 16) / 256, 256, 0, stream>>>(x, table, out);
    }
}